// Round 1
// baseline (215.716 us; speedup 1.0000x reference)
//
#include <hip/hip_runtime.h>
#include <math.h>

#define Q_MAX 127.0f
#define D 11008          // half of 22016
#define NVEC (D / 4)     // 2752 float4 per row
#define BLOCK 256
#define ITERS 11         // ceil(2752 / 256)

__global__ __launch_bounds__(BLOCK) void silu_mul_quant_kernel(
    const float* __restrict__ x,
    float* __restrict__ q_out,      // rows*D floats (int values as f32)
    float* __restrict__ scale_out,  // rows floats
    float* __restrict__ sum_out)    // rows floats
{
    const int row = blockIdx.x;
    const int tid = threadIdx.x;

    const float4* gate4 = reinterpret_cast<const float4*>(x + (size_t)row * (2 * D));
    const float4* up4   = reinterpret_cast<const float4*>(x + (size_t)row * (2 * D) + D);
    float4* q4          = reinterpret_cast<float4*>(q_out + (size_t)row * D);

    float4 v[ITERS];
    float lmax = 0.0f;
    float lsum = 0.0f;

    // Pass A: load gate/up, compute out = silu(gate)*up, cache in registers,
    // accumulate per-thread absmax and sum.
    #pragma unroll
    for (int i = 0; i < ITERS; ++i) {
        const int idx = i * BLOCK + tid;
        if (idx < NVEC) {
            const float4 g = gate4[idx];
            const float4 u = up4[idx];
            float4 o;
            // silu(g)*u = g*u / (1 + exp(-g)); __expf -> v_exp_f32 (cheap)
            o.x = __fdividef(g.x * u.x, 1.0f + __expf(-g.x));
            o.y = __fdividef(g.y * u.y, 1.0f + __expf(-g.y));
            o.z = __fdividef(g.z * u.z, 1.0f + __expf(-g.z));
            o.w = __fdividef(g.w * u.w, 1.0f + __expf(-g.w));
            v[i] = o;
            lmax = fmaxf(lmax, fmaxf(fmaxf(fabsf(o.x), fabsf(o.y)),
                                     fmaxf(fabsf(o.z), fabsf(o.w))));
            lsum += (o.x + o.y) + (o.z + o.w);
        }
    }

    // Wave (64-lane) butterfly reduction, then cross-wave via tiny LDS.
    #pragma unroll
    for (int off = 32; off > 0; off >>= 1) {
        lmax = fmaxf(lmax, __shfl_xor(lmax, off));
        lsum += __shfl_xor(lsum, off);
    }

    __shared__ float red_max[4];
    __shared__ float red_sum[4];
    const int wave = tid >> 6;
    const int lane = tid & 63;
    if (lane == 0) {
        red_max[wave] = lmax;
        red_sum[wave] = lsum;
    }
    __syncthreads();

    const float absmax = fmaxf(fmaxf(red_max[0], red_max[1]),
                               fmaxf(red_max[2], red_max[3]));
    const float total  = (red_sum[0] + red_sum[1]) + (red_sum[2] + red_sum[3]);

    if (tid == 0) {
        scale_out[row] = absmax / Q_MAX;   // exactly as reference computes scale
        sum_out[row]   = total;
    }

    const float inv = (absmax > 0.0f) ? (Q_MAX / absmax) : 0.0f;

    // Pass B: quantize from registers, write as float32 values.
    #pragma unroll
    for (int i = 0; i < ITERS; ++i) {
        const int idx = i * BLOCK + tid;
        if (idx < NVEC) {
            const float4 o = v[i];
            float4 q;
            q.x = fminf(fmaxf(rintf(o.x * inv), -128.0f), Q_MAX);
            q.y = fminf(fmaxf(rintf(o.y * inv), -128.0f), Q_MAX);
            q.z = fminf(fmaxf(rintf(o.z * inv), -128.0f), Q_MAX);
            q.w = fminf(fmaxf(rintf(o.w * inv), -128.0f), Q_MAX);
            q4[idx] = q;
        }
    }
}

extern "C" void kernel_launch(void* const* d_in, const int* in_sizes, int n_in,
                              void* d_out, int out_size, void* d_ws, size_t ws_size,
                              hipStream_t stream) {
    const float* x = (const float*)d_in[0];
    const int rows = in_sizes[0] / (2 * D);   // 8192

    float* out       = (float*)d_out;
    float* q_out     = out;                         // rows*D
    float* scale_out = out + (size_t)rows * D;      // rows
    float* sum_out   = scale_out + rows;            // rows

    silu_mul_quant_kernel<<<dim3(rows), dim3(BLOCK), 0, stream>>>(
        x, q_out, scale_out, sum_out);
}

// Round 2
// 182.990 us; speedup vs baseline: 1.1788x; 1.1788x over previous
//
#include <hip/hip_runtime.h>
#include <math.h>

#define Q_MAX 127.0f
#define D 11008                      // half of 22016
#define NVEC (D / 4)                 // 2752 float4 per row
#define BLOCK 512
#define WAVES (BLOCK / 64)           // 8 waves per block
#define FULL 5                       // 5*512 = 2560 <= 2752, unconditional iters
#define TAIL_N (NVEC - FULL * BLOCK) // 192 remaining vectors

typedef float f4 __attribute__((ext_vector_type(4)));

__global__ __launch_bounds__(BLOCK) void silu_mul_quant_kernel(
    const float* __restrict__ x,
    float* __restrict__ q_out,      // rows*D floats (int values as f32)
    float* __restrict__ scale_out,  // rows floats
    float* __restrict__ sum_out)    // rows floats
{
    const int row = blockIdx.x;
    const int tid = threadIdx.x;

    const f4* gate4 = reinterpret_cast<const f4*>(x + (size_t)row * (2 * D));
    const f4* up4   = gate4 + NVEC;                       // +D floats
    f4* q4          = reinterpret_cast<f4*>(q_out + (size_t)row * D);

    f4 v[FULL + 1];
    float lmax = 0.0f;
    float lsum = 0.0f;

    // Pass A: streaming (non-temporal) loads, silu(gate)*up cached in regs,
    // per-thread absmax & sum.
    #pragma unroll
    for (int i = 0; i < FULL; ++i) {
        const int idx = i * BLOCK + tid;
        const f4 g = __builtin_nontemporal_load(&gate4[idx]);
        const f4 u = __builtin_nontemporal_load(&up4[idx]);
        f4 o;
        o.x = __fdividef(g.x * u.x, 1.0f + __expf(-g.x));
        o.y = __fdividef(g.y * u.y, 1.0f + __expf(-g.y));
        o.z = __fdividef(g.z * u.z, 1.0f + __expf(-g.z));
        o.w = __fdividef(g.w * u.w, 1.0f + __expf(-g.w));
        v[i] = o;
        lmax = fmaxf(lmax, fmaxf(fmaxf(fabsf(o.x), fabsf(o.y)),
                                 fmaxf(fabsf(o.z), fabsf(o.w))));
        lsum += (o.x + o.y) + (o.z + o.w);
    }
    const bool has_tail = (tid < TAIL_N);
    if (has_tail) {
        const int idx = FULL * BLOCK + tid;
        const f4 g = __builtin_nontemporal_load(&gate4[idx]);
        const f4 u = __builtin_nontemporal_load(&up4[idx]);
        f4 o;
        o.x = __fdividef(g.x * u.x, 1.0f + __expf(-g.x));
        o.y = __fdividef(g.y * u.y, 1.0f + __expf(-g.y));
        o.z = __fdividef(g.z * u.z, 1.0f + __expf(-g.z));
        o.w = __fdividef(g.w * u.w, 1.0f + __expf(-g.w));
        v[FULL] = o;
        lmax = fmaxf(lmax, fmaxf(fmaxf(fabsf(o.x), fabsf(o.y)),
                                 fmaxf(fabsf(o.z), fabsf(o.w))));
        lsum += (o.x + o.y) + (o.z + o.w);
    }

    // Wave (64-lane) butterfly reduction, then cross-wave via tiny LDS.
    #pragma unroll
    for (int off = 32; off > 0; off >>= 1) {
        lmax = fmaxf(lmax, __shfl_xor(lmax, off));
        lsum += __shfl_xor(lsum, off);
    }

    __shared__ float red_max[WAVES];
    __shared__ float red_sum[WAVES];
    const int wave = tid >> 6;
    const int lane = tid & 63;
    if (lane == 0) {
        red_max[wave] = lmax;
        red_sum[wave] = lsum;
    }
    __syncthreads();

    float absmax = red_max[0];
    float total  = red_sum[0];
    #pragma unroll
    for (int w = 1; w < WAVES; ++w) {
        absmax = fmaxf(absmax, red_max[w]);
        total += red_sum[w];
    }

    if (tid == 0) {
        scale_out[row] = absmax / Q_MAX;   // exactly as reference computes scale
        sum_out[row]   = total;
    }

    const float inv = (absmax > 0.0f) ? (Q_MAX / absmax) : 0.0f;

    // Pass B: quantize from registers, streaming stores.
    #pragma unroll
    for (int i = 0; i < FULL; ++i) {
        const int idx = i * BLOCK + tid;
        const f4 o = v[i];
        f4 q;
        q.x = fminf(fmaxf(rintf(o.x * inv), -128.0f), Q_MAX);
        q.y = fminf(fmaxf(rintf(o.y * inv), -128.0f), Q_MAX);
        q.z = fminf(fmaxf(rintf(o.z * inv), -128.0f), Q_MAX);
        q.w = fminf(fmaxf(rintf(o.w * inv), -128.0f), Q_MAX);
        __builtin_nontemporal_store(q, &q4[idx]);
    }
    if (has_tail) {
        const int idx = FULL * BLOCK + tid;
        const f4 o = v[FULL];
        f4 q;
        q.x = fminf(fmaxf(rintf(o.x * inv), -128.0f), Q_MAX);
        q.y = fminf(fmaxf(rintf(o.y * inv), -128.0f), Q_MAX);
        q.z = fminf(fmaxf(rintf(o.z * inv), -128.0f), Q_MAX);
        q.w = fminf(fmaxf(rintf(o.w * inv), -128.0f), Q_MAX);
        __builtin_nontemporal_store(q, &q4[idx]);
    }
}

extern "C" void kernel_launch(void* const* d_in, const int* in_sizes, int n_in,
                              void* d_out, int out_size, void* d_ws, size_t ws_size,
                              hipStream_t stream) {
    const float* x = (const float*)d_in[0];
    const int rows = in_sizes[0] / (2 * D);   // 8192

    float* out       = (float*)d_out;
    float* q_out     = out;                         // rows*D
    float* scale_out = out + (size_t)rows * D;      // rows
    float* sum_out   = scale_out + rows;            // rows

    silu_mul_quant_kernel<<<dim3(rows), dim3(BLOCK), 0, stream>>>(
        x, q_out, scale_out, sum_out);
}